// Round 4
// baseline (898.060 us; speedup 1.0000x reference)
//
#include <hip/hip_runtime.h>

// Conv2d(8->64,3x3,VALID)+bias -> GroupNorm(16) -> scale[c] -> MaxPool4x4 -> clip[0,1]
// x: [32,8,256,256] f32 -> out: [32,64,63,63] f32.
//
// R4: conv as bf16-split MFMA GEMM (mfma_f32_32x32x16_bf16).
//  K = taps(9)*ic(8) padded to 80 (tap9 weights = 0). x staged to LDS as
//  [row][px][8ic-hi|8ic-lo] bf16 (transpose+split in staging). Weights resident
//  as A-fragments (2 oc-tiles x 5 Ksteps x hi/lo = 80 VGPR). 3-term split:
//  y ~= xh*wh + xl*wh + xh*wl. Raw 4x4 pool maxima -> d_out (GN affine A>0
//  commutes with max); per-(b,group) biased sum/sumsq -> atomics; finalize pass
//  applies clamp(A*raw+B).

typedef __attribute__((ext_vector_type(8))) short bf16x8;
typedef __attribute__((ext_vector_type(16))) float f32x16;

#define NPIX 258064.0f  // 4 * 254 * 254 per (b, group)

__device__ __forceinline__ unsigned short f2bf(float f) {
    unsigned u = __float_as_uint(f);
    u += 0x7FFFu + ((u >> 16) & 1u);
    return (unsigned short)(u >> 16);
}
__device__ __forceinline__ float bf2f(unsigned short h) {
    return __uint_as_float(((unsigned)h) << 16);
}
__device__ __forceinline__ float dppmax(float v, const int ctrl) {
    int o;
    if (ctrl == 0xB1) o = __builtin_amdgcn_mov_dpp(__float_as_int(v), 0xB1, 0xF, 0xF, true);
    else              o = __builtin_amdgcn_mov_dpp(__float_as_int(v), 0x4E, 0xF, 0xF, true);
    return fmaxf(v, __int_as_float(o));
}

__global__ __launch_bounds__(256) void conv_mfma(
    const float* __restrict__ x, const float* __restrict__ cw,
    const float* __restrict__ cb, float* __restrict__ pooled,
    float* __restrict__ stats)
{
    __shared__ __align__(16) unsigned char xs[7 * 66 * 48];   // 22176 B: [row][px][hi16|lo16|pad16]
    __shared__ __align__(16) unsigned short wt[2 * 64 * 80];  // 20480 B: [half][oc][k=tap*8+ic]
    __shared__ float pool_lds[4 * 16 * 65];                   // 16640 B

    const int tid = threadIdx.x;
    const int l = tid & 63, w = tid >> 6;     // wave w owns output row R0+w
    const int ll = l & 31, hh5 = l >> 5;
    const int C0 = blockIdx.x * 64;
    const int tileY = blockIdx.y;             // pooled row
    const int R0 = tileY * 4;
    const int b = blockIdx.z;

    // ---- stage weights: cw[oc][ic][kh][kw] -> wt[half][oc][tap*8+ic], k>=72 zero ----
    for (int i = tid; i < 5120; i += 256) {
        int oc = i / 80, k = i - oc * 80;
        float wv = 0.0f;
        if (k < 72) { int tap = k >> 3, ic = k & 7; wv = cw[oc * 72 + ic * 9 + tap]; }
        unsigned short h = f2bf(wv);
        unsigned short lo = f2bf(wv - bf2f(h));
        wt[i] = h; wt[5120 + i] = lo;
    }
    // ---- stage x tile: transpose [ic][h][w] -> [row][px][ic], split hi/lo bf16 ----
    const float* xb = x + (size_t)b * 524288;
    for (int i = tid; i < 462; i += 256) {     // 7 rows x 66 px
        int row = i / 66, px = i - row * 66;
        int gr = R0 + row, gc = C0 + px;
        bool ok = (gr < 256) && (gc < 256);
        const float* p = xb + gr * 256 + gc;
        unsigned hi[4], lo[4];
        #pragma unroll
        for (int j = 0; j < 4; ++j) {
            float v0 = ok ? p[(2 * j) * 65536] : 0.0f;
            float v1 = ok ? p[(2 * j + 1) * 65536] : 0.0f;
            unsigned short h0 = f2bf(v0), h1 = f2bf(v1);
            unsigned short l0 = f2bf(v0 - bf2f(h0)), l1 = f2bf(v1 - bf2f(h1));
            hi[j] = (unsigned)h0 | ((unsigned)h1 << 16);
            lo[j] = (unsigned)l0 | ((unsigned)l1 << 16);
        }
        uint4* dst = (uint4*)(xs + i * 48);
        dst[0] = make_uint4(hi[0], hi[1], hi[2], hi[3]);
        dst[1] = make_uint4(lo[0], lo[1], lo[2], lo[3]);
    }
    __syncthreads();

    // ---- A fragments (weights) resident in registers ----
    bf16x8 af[2][5][2];
    #pragma unroll
    for (int oct = 0; oct < 2; ++oct)
        #pragma unroll
        for (int s = 0; s < 5; ++s)
            #pragma unroll
            for (int hf = 0; hf < 2; ++hf) {
                int idx = hf * 5120 + (oct * 32 + ll) * 80 + s * 16 + hh5 * 8;
                af[oct][s][hf] = *(const bf16x8*)(wt + idx);
            }

    float sacc[8], qacc[8];
    #pragma unroll
    for (int j = 0; j < 8; ++j) { sacc[j] = 0.0f; qacc[j] = 0.0f; }

    const bool rowOK = (R0 + w) < 254;        // wave-uniform
    const bool poolOK = (tileY < 63);         // block-uniform

    if (rowOK) {
        // per-Kstep tap for this lane half: h=0 -> tap 2s, h=1 -> tap 2s+1
        const int KHe[5] = {0, 0, 1, 2, 2}, KWe[5] = {0, 2, 1, 0, 2};   // taps 0,2,4,6,8
        const int KHo[5] = {0, 1, 1, 2, 3}, KWo[5] = {1, 0, 2, 1, 0};   // taps 1,3,5,7,9(pad)
        int off[5];
        #pragma unroll
        for (int s = 0; s < 5; ++s) {
            int kh = hh5 ? KHo[s] : KHe[s];
            int kw = hh5 ? KWo[s] : KWe[s];
            off[s] = ((w + kh) * 66 + ll + kw) * 48;
        }

        #pragma unroll 1
        for (int owt = 0; owt < 2; ++owt) {
            f32x16 acc0, acc1;
            #pragma unroll
            for (int j = 0; j < 16; ++j) { acc0[j] = 0.0f; acc1[j] = 0.0f; }
            const int obase = owt * 1536;       // owt*32 px * 48B

            #pragma unroll
            for (int s = 0; s < 5; ++s) {
                bf16x8 Bh = *(const bf16x8*)(xs + off[s] + obase);
                bf16x8 Bl = *(const bf16x8*)(xs + off[s] + obase + 16);
                acc0 = __builtin_amdgcn_mfma_f32_32x32x16_bf16(af[0][s][0], Bh, acc0, 0, 0, 0);
                acc1 = __builtin_amdgcn_mfma_f32_32x32x16_bf16(af[1][s][0], Bh, acc1, 0, 0, 0);
                acc0 = __builtin_amdgcn_mfma_f32_32x32x16_bf16(af[0][s][1], Bh, acc0, 0, 0, 0);
                acc1 = __builtin_amdgcn_mfma_f32_32x32x16_bf16(af[1][s][1], Bh, acc1, 0, 0, 0);
                acc0 = __builtin_amdgcn_mfma_f32_32x32x16_bf16(af[0][s][0], Bl, acc0, 0, 0, 0);
                acc1 = __builtin_amdgcn_mfma_f32_32x32x16_bf16(af[1][s][0], Bl, acc1, 0, 0, 0);
            }

            // ---- epilogue: bias + stats + per-row pool max ----
            const int gpx = C0 + owt * 32 + ll;
            const bool pxOK = (gpx < 254);
            const int pcl = owt * 8 + (ll >> 2);
            const bool doStore = poolOK && ((ll & 3) == 0);
            #pragma unroll
            for (int oct = 0; oct < 2; ++oct) {
                #pragma unroll
                for (int r = 0; r < 16; ++r) {
                    const int ocb = oct * 32 + (r & 3) + 8 * (r >> 2);  // + 4*hh5 = C row
                    const float blo = cb[ocb], bhi = cb[ocb + 4];        // uniform s_loads
                    const float a = oct ? acc1[r] : acc0[r];
                    float v = a + (hh5 ? bhi : blo);
                    float vm = pxOK ? v : 0.0f;
                    sacc[oct * 4 + (r >> 2)] += vm;
                    qacc[oct * 4 + (r >> 2)] = fmaf(vm, vm, qacc[oct * 4 + (r >> 2)]);
                    if (poolOK) {
                        float pv = dppmax(v, 0xB1);   // xor 1 (quad_perm 1,0,3,2)
                        pv = dppmax(pv, 0x4E);        // xor 2 (quad_perm 2,3,0,1)
                        if (doStore) pool_lds[(w * 16 + pcl) * 65 + ocb + 4 * hh5] = pv;
                    }
                }
            }
        }

        // ---- stats reduce (within 32-lane halves; halves hold even/odd groups) ----
        #pragma unroll
        for (int m = 1; m <= 16; m <<= 1) {
            #pragma unroll
            for (int j = 0; j < 8; ++j) {
                sacc[j] += __shfl_xor(sacc[j], m, 64);
                qacc[j] += __shfl_xor(qacc[j], m, 64);
            }
        }
        if ((l & 31) == 0) {
            #pragma unroll
            for (int j = 0; j < 8; ++j) {
                int g = (j >> 2) * 8 + 2 * (j & 3) + hh5;
                atomicAdd(&stats[b * 16 + g], sacc[j]);
                atomicAdd(&stats[512 + b * 16 + g], qacc[j]);
            }
        }
    }

    __syncthreads();
    // ---- cross-wave pool reduce (4 oh rows) + store raw maxima ----
    if (tileY < 63) {
        #pragma unroll
        for (int k = 0; k < 4; ++k) {
            int idx = k * 256 + tid;
            int pc = idx & 15, oc = idx >> 4;
            float m0 = pool_lds[(0 * 16 + pc) * 65 + oc];
            float m1 = pool_lds[(1 * 16 + pc) * 65 + oc];
            float m2 = pool_lds[(2 * 16 + pc) * 65 + oc];
            float m3 = pool_lds[(3 * 16 + pc) * 65 + oc];
            float m = fmaxf(fmaxf(m0, m1), fmaxf(m2, m3));
            int pcol = (C0 >> 2) + pc;
            if (pcol < 63)
                pooled[((b * 64 + oc) * 63 + tileY) * 63 + pcol] = m;
        }
    }
}

__global__ __launch_bounds__(256) void finalize_affine_clamp(
    float* __restrict__ out, const float* __restrict__ stats,
    const float* __restrict__ gnw, const float* __restrict__ gnb,
    const float* __restrict__ scale)
{
    const int bc = blockIdx.y;                 // 0..2047
    const int b = bc >> 6, c = bc & 63, g = c >> 2;
    const float sum = stats[b * 16 + g];
    const float ssq = stats[512 + b * 16 + g];
    const float invN = 1.0f / NPIX;
    const float mean = sum * invN;
    const float var  = ssq * invN - mean * mean;
    const float rs   = rsqrtf(var + 1e-5f);
    const float A  = rs * gnw[c] * scale[c];
    const float Bv = (gnb[c] - mean * rs * gnw[c]) * scale[c];
    const int base = bc * 3969;
    #pragma unroll
    for (int k = 0; k < 4; ++k) {
        int e = blockIdx.x * 1024 + k * 256 + threadIdx.x;
        if (e < 3969) {
            float v = fmaf(A, out[base + e], Bv);
            out[base + e] = fminf(fmaxf(v, 0.0f), 1.0f);
        }
    }
}

extern "C" void kernel_launch(void* const* d_in, const int* in_sizes, int n_in,
                              void* d_out, int out_size, void* d_ws, size_t ws_size,
                              hipStream_t stream) {
    const float* x     = (const float*)d_in[0];
    const float* cw    = (const float*)d_in[1];
    const float* cb    = (const float*)d_in[2];
    const float* gnw   = (const float*)d_in[3];
    const float* gnb   = (const float*)d_in[4];
    const float* scale = (const float*)d_in[5];
    float* out   = (float*)d_out;
    float* stats = (float*)d_ws;

    hipMemsetAsync(d_ws, 0, 1024 * sizeof(float), stream);

    dim3 grid1(4, 64, 32);
    conv_mfma<<<grid1, 256, 0, stream>>>(x, cw, cb, out, stats);

    dim3 grid2(4, 2048, 1);
    finalize_affine_clamp<<<grid2, 256, 0, stream>>>(out, stats, gnw, gnb, scale);
}

// Round 5
// 419.656 us; speedup vs baseline: 2.1400x; 2.1400x over previous
//
#include <hip/hip_runtime.h>

// Conv2d(8->64,3x3,VALID)+bias -> GroupNorm(16) -> scale[c] -> MaxPool4x4 -> clip[0,1]
// x: [32,8,256,256] f32 -> out: [32,64,63,63] f32.
//
// R5: bf16-split MFMA conv (mfma_f32_32x32x16_bf16), restructured vs R4 to kill
// scratch spills (R4: 80-reg A-frags + 104-reg budget -> spill storm, MfmaUtil 3%).
//  - wave = 32 oc x 32 px x 4 rows: A-frags 10 (40 VGPR), one acc chain (16 VGPR)
//  - pool intra-wave (reg max over rows, dpp over px quads) -> no pool LDS, one sync
//  - tap9 pad -> (kh0,kw0): only 6 staged rows; LDS 39.5KB -> 4 blocks/CU
//  - finalize: prep A,B per (b,c) then float4 + uniform-quad fast path

typedef __attribute__((ext_vector_type(8))) short bf16x8;
typedef __attribute__((ext_vector_type(16))) float f32x16;

#define NPIX 258064.0f  // 4 * 254 * 254 per (b, group)

__device__ __forceinline__ unsigned short f2bf(float f) {
    unsigned u = __float_as_uint(f);
    u += 0x7FFFu + ((u >> 16) & 1u);
    return (unsigned short)(u >> 16);
}
__device__ __forceinline__ float bf2f(unsigned short h) {
    return __uint_as_float(((unsigned)h) << 16);
}
__device__ __forceinline__ float dppmax(float v, const int ctrl) {
    int o;
    if (ctrl == 0xB1) o = __builtin_amdgcn_mov_dpp(__float_as_int(v), 0xB1, 0xF, 0xF, true);
    else              o = __builtin_amdgcn_mov_dpp(__float_as_int(v), 0x4E, 0xF, 0xF, true);
    return fmaxf(v, __int_as_float(o));
}

__global__ __launch_bounds__(256, 4) void conv_mfma(
    const float* __restrict__ x, const float* __restrict__ cw,
    const float* __restrict__ cb, float* __restrict__ pooled,
    float* __restrict__ stats)
{
    __shared__ __align__(16) unsigned char xs[6 * 66 * 48];   // 19008 B [row][px][hi16|lo16|pad16]
    __shared__ __align__(16) unsigned short wt[2 * 64 * 80];  // 20480 B [half][oc][tap*8+ic]

    const int tid = threadIdx.x;
    const int l = tid & 63, w = tid >> 6;
    const int ll = l & 31, hh5 = l >> 5;
    const int po = w & 1;                     // px segment (32*po)
    const int ot = w >> 1;                    // oc tile (32*ot)
    const int C0 = blockIdx.x * 64;
    const int tileY = blockIdx.y;             // pooled row
    const int R0 = tileY * 4;
    const int b = blockIdx.z;

    // ---- stage weights: cw[oc][ic][kh][kw] -> wt[half][oc][tap*8+ic], k>=72 zero ----
    for (int i = tid; i < 5120; i += 256) {
        int oc = i / 80, k = i - oc * 80;
        float wv = 0.0f;
        if (k < 72) { int tap = k >> 3, ic = k & 7; wv = cw[oc * 72 + ic * 9 + tap]; }
        unsigned short h = f2bf(wv);
        unsigned short lo = f2bf(wv - bf2f(h));
        wt[i] = h; wt[5120 + i] = lo;
    }
    // ---- stage x: 6 rows x 66 px, transpose to [row][px][8ic], split hi/lo ----
    const float* xb = x + (size_t)b * 524288;
    for (int i = tid; i < 396; i += 256) {
        int row = i / 66, px = i - row * 66;
        int gr = R0 + row, gc = C0 + px;
        bool ok = (gr < 256) && (gc < 256);
        const float* p = xb + gr * 256 + gc;
        unsigned hi[4], lo[4];
        #pragma unroll
        for (int j = 0; j < 4; ++j) {
            float v0 = ok ? p[(2 * j) * 65536] : 0.0f;
            float v1 = ok ? p[(2 * j + 1) * 65536] : 0.0f;
            unsigned short h0 = f2bf(v0), h1 = f2bf(v1);
            unsigned short l0 = f2bf(v0 - bf2f(h0)), l1 = f2bf(v1 - bf2f(h1));
            hi[j] = (unsigned)h0 | ((unsigned)h1 << 16);
            lo[j] = (unsigned)l0 | ((unsigned)l1 << 16);
        }
        uint4* dst = (uint4*)(xs + i * 48);
        dst[0] = make_uint4(hi[0], hi[1], hi[2], hi[3]);
        dst[1] = make_uint4(lo[0], lo[1], lo[2], lo[3]);
    }
    __syncthreads();

    // ---- A fragments: this wave's oc tile only (10 frags = 40 VGPR) ----
    bf16x8 afH[5], afL[5];
    #pragma unroll
    for (int s = 0; s < 5; ++s) {
        int idx = (ot * 32 + ll) * 80 + s * 16 + hh5 * 8;
        afH[s] = *(const bf16x8*)(wt + idx);
        afL[s] = *(const bf16x8*)(wt + 5120 + idx);
    }

    // per-Kstep tap for this lane half: hh5=0 -> taps 0,2,4,6,8 ; hh5=1 -> 1,3,5,7,pad
    const int KHe[5] = {0, 0, 1, 2, 2}, KWe[5] = {0, 2, 1, 0, 2};
    const int KHo[5] = {0, 1, 1, 2, 0}, KWo[5] = {1, 0, 2, 1, 0};  // pad tap -> (0,0), w=0
    int baseOff[5];
    #pragma unroll
    for (int s = 0; s < 5; ++s) {
        int kh = hh5 ? KHo[s] : KHe[s];
        int kw = hh5 ? KWo[s] : KWe[s];
        baseOff[s] = kh * 3168 + (po * 32 + ll + kw) * 48;
    }

    const bool pxV = (C0 + po * 32 + ll) < 254;
    float pm[16];
    float sacc[4] = {0.f, 0.f, 0.f, 0.f}, qacc[4] = {0.f, 0.f, 0.f, 0.f};
    #pragma unroll
    for (int j = 0; j < 16; ++j) pm[j] = -3.4e38f;

    #pragma unroll 1
    for (int r = 0; r < 4; ++r) {
        f32x16 acc;
        #pragma unroll
        for (int j = 0; j < 16; ++j) acc[j] = 0.0f;
        const unsigned char* xr = xs + r * 3168;
        #pragma unroll
        for (int s = 0; s < 5; ++s) {
            bf16x8 Bh = *(const bf16x8*)(xr + baseOff[s]);
            bf16x8 Bl = *(const bf16x8*)(xr + baseOff[s] + 16);
            acc = __builtin_amdgcn_mfma_f32_32x32x16_bf16(afH[s], Bh, acc, 0, 0, 0);
            acc = __builtin_amdgcn_mfma_f32_32x32x16_bf16(afL[s], Bh, acc, 0, 0, 0);
            acc = __builtin_amdgcn_mfma_f32_32x32x16_bf16(afH[s], Bl, acc, 0, 0, 0);
        }
        const bool sv = ((R0 + r) < 254) && pxV;
        #pragma unroll
        for (int reg = 0; reg < 16; ++reg) {
            const int ocb = ot * 32 + (reg & 3) + 8 * (reg >> 2);
            const float blo = cb[ocb], bhi = cb[ocb + 4];   // uniform s_loads
            float v = acc[reg] + (hh5 ? bhi : blo);
            pm[reg] = fmaxf(pm[reg], v);
            float vm = sv ? v : 0.0f;
            sacc[reg >> 2] += vm;
            qacc[reg >> 2] = fmaf(vm, vm, qacc[reg >> 2]);
        }
    }

    // ---- pool across px quads (in-wave) + store raw maxima ----
    #pragma unroll
    for (int reg = 0; reg < 16; ++reg) {
        float m = dppmax(pm[reg], 0xB1);   // xor 1
        pm[reg] = dppmax(m, 0x4E);         // xor 2
    }
    const int pcol = blockIdx.x * 16 + po * 8 + (ll >> 2);
    if (tileY < 63 && (ll & 3) == 0 && pcol < 63) {
        #pragma unroll
        for (int reg = 0; reg < 16; ++reg) {
            int oc = ot * 32 + (reg & 3) + 8 * (reg >> 2) + 4 * hh5;
            pooled[((b * 64 + oc) * 63 + tileY) * 63 + pcol] = pm[reg];
        }
    }

    // ---- stats reduce within 32-lane halves (halves hold even/odd groups) ----
    #pragma unroll
    for (int m = 1; m <= 16; m <<= 1) {
        #pragma unroll
        for (int j = 0; j < 4; ++j) {
            sacc[j] += __shfl_xor(sacc[j], m, 64);
            qacc[j] += __shfl_xor(qacc[j], m, 64);
        }
    }
    if (ll == 0) {
        #pragma unroll
        for (int j = 0; j < 4; ++j) {
            int g = ot * 8 + 2 * j + hh5;
            atomicAdd(&stats[b * 16 + g], sacc[j]);
            atomicAdd(&stats[512 + b * 16 + g], qacc[j]);
        }
    }
}

__global__ __launch_bounds__(256) void prep_params(
    const float* __restrict__ stats, const float* __restrict__ gnw,
    const float* __restrict__ gnb, const float* __restrict__ scale,
    float* __restrict__ AB)
{
    const int bc = blockIdx.x * 256 + threadIdx.x;
    if (bc >= 2048) return;
    const int b = bc >> 6, c = bc & 63, g = c >> 2;
    const float sum = stats[b * 16 + g];
    const float ssq = stats[512 + b * 16 + g];
    const float invN = 1.0f / NPIX;
    const float mean = sum * invN;
    const float var  = ssq * invN - mean * mean;
    const float rs   = rsqrtf(var + 1e-5f);
    AB[bc]        = rs * gnw[c] * scale[c];
    AB[2048 + bc] = (gnb[c] - mean * rs * gnw[c]) * scale[c];
}

__global__ __launch_bounds__(256) void finalize_affine_clamp(
    float* __restrict__ out, const float* __restrict__ AB)
{
    const int t = blockIdx.x * 256 + threadIdx.x;    // float4 index
    if (t >= 2032128) return;                        // 32*64*3969/4
    float4 v = reinterpret_cast<float4*>(out)[t];
    const int I0 = t * 4;
    const int bc0 = I0 / 3969;                       // magic-div
    const int bc3 = (I0 + 3) / 3969;
    if (bc0 == bc3) {
        const float A = AB[bc0], B = AB[2048 + bc0];
        v.x = fminf(fmaxf(fmaf(A, v.x, B), 0.f), 1.f);
        v.y = fminf(fmaxf(fmaf(A, v.y, B), 0.f), 1.f);
        v.z = fminf(fmaxf(fmaf(A, v.z, B), 0.f), 1.f);
        v.w = fminf(fmaxf(fmaf(A, v.w, B), 0.f), 1.f);
    } else {
        float r[4] = {v.x, v.y, v.z, v.w};
        #pragma unroll
        for (int j = 0; j < 4; ++j) {
            const int bc = (I0 + j) / 3969;
            const float A = AB[bc], B = AB[2048 + bc];
            r[j] = fminf(fmaxf(fmaf(A, r[j], B), 0.f), 1.f);
        }
        v = make_float4(r[0], r[1], r[2], r[3]);
    }
    reinterpret_cast<float4*>(out)[t] = v;
}

extern "C" void kernel_launch(void* const* d_in, const int* in_sizes, int n_in,
                              void* d_out, int out_size, void* d_ws, size_t ws_size,
                              hipStream_t stream) {
    const float* x     = (const float*)d_in[0];
    const float* cw    = (const float*)d_in[1];
    const float* cb    = (const float*)d_in[2];
    const float* gnw   = (const float*)d_in[3];
    const float* gnb   = (const float*)d_in[4];
    const float* scale = (const float*)d_in[5];
    float* out   = (float*)d_out;
    float* stats = (float*)d_ws;                   // 1024 floats
    float* AB    = (float*)d_ws + 1024;            // 4096 floats

    hipMemsetAsync(d_ws, 0, 1024 * sizeof(float), stream);

    dim3 grid1(4, 64, 32);
    conv_mfma<<<grid1, 256, 0, stream>>>(x, cw, cb, out, stats);

    prep_params<<<8, 256, 0, stream>>>(stats, gnw, gnb, scale, AB);

    finalize_affine_clamp<<<(2032128 + 255) / 256, 256, 0, stream>>>(out, AB);
}

// Round 7
// 264.053 us; speedup vs baseline: 3.4011x; 1.5893x over previous
//
#include <hip/hip_runtime.h>

// Conv2d(8->64,3x3,VALID)+bias -> GroupNorm(16) -> scale[c] -> MaxPool4x4 -> clip[0,1]
// x: [32,8,256,256] f32 -> out: [32,64,63,63] f32.
//
// R6: bf16-split MFMA conv, latency-amortized.
//  - prep_weights: one-time conversion of cw+cb into A-fragment-ordered bf16 hi/lo
//    (10240 ushort in d_ws). Conv blocks load 10 frags via coalesced dwordx4 (L2).
//  - bias folded into MFMA via pad K-slot k=72 (weight=bias hi/lo, B=1.0 from a
//    broadcast "ones" LDS slot) -> no epilogue bias add.
//  - block = 64px x 16 conv rows (2 pooled rows): 120 MFMA/wave, one barrier,
//    LDS 31.7KB -> 5 blocks/CU.
//  - pool intra-wave (reg max over rows, dpp over px quads); GN affine A>0 commutes
//    with maxpool; finalize applies clamp(A*raw+B) per (b,c) block.

typedef __attribute__((ext_vector_type(8))) short bf16x8;
typedef __attribute__((ext_vector_type(16))) float f32x16;

#define NPIX 258064.0f   // 4 * 254 * 254 per (b, group)
#define ONES_OFF 31680   // byte offset of the B=1.0 slot in xs

__device__ __forceinline__ unsigned short f2bf_rne(float f) {
    unsigned u = __float_as_uint(f);
    u += 0x7FFFu + ((u >> 16) & 1u);
    return (unsigned short)(u >> 16);
}
__device__ __forceinline__ float bf2f(unsigned short h) {
    return __uint_as_float(((unsigned)h) << 16);
}
__device__ __forceinline__ float dppmax(float v, const int ctrl) {
    int o;
    if (ctrl == 0xB1) o = __builtin_amdgcn_mov_dpp(__float_as_int(v), 0xB1, 0xF, 0xF, true);
    else              o = __builtin_amdgcn_mov_dpp(__float_as_int(v), 0x4E, 0xF, 0xF, true);
    return fmaxf(v, __int_as_float(o));
}

// ---- one-time weight prep: wg[(s*2+half)*1024 + ot*512 + lane*8 + j] ----
__global__ __launch_bounds__(256) void prep_weights(
    const float* __restrict__ cw, const float* __restrict__ cb,
    unsigned short* __restrict__ wg)
{
    const int e = blockIdx.x * 256 + threadIdx.x;
    if (e >= 10240) return;
    const int j = e & 7, lane = (e >> 3) & 63, ot = (e >> 9) & 1;
    const int half = (e >> 10) & 1, s = e >> 11;
    const int oc = ot * 32 + (lane & 31), hh5 = lane >> 5;
    const int k = s * 16 + hh5 * 8 + j;
    float wv = 0.0f;
    if (k < 72)       wv = cw[oc * 72 + (k & 7) * 9 + (k >> 3)];
    else if (k == 72) wv = cb[oc];          // bias rides the pad K-slot
    const unsigned short hi = f2bf_rne(wv);
    const unsigned short lo = f2bf_rne(wv - bf2f(hi));
    wg[e] = half ? lo : hi;
}

__global__ __launch_bounds__(256, 4) void conv_mfma(
    const float* __restrict__ x, const unsigned short* __restrict__ wg,
    float* __restrict__ pooled, float* __restrict__ stats)
{
    __shared__ __align__(16) unsigned char xs[10 * 66 * 48 + 32];  // 31712 B

    const int tid = threadIdx.x;
    const int l = tid & 63, w = tid >> 6;
    const int ll = l & 31, hh5 = l >> 5;
    const int po = w & 1, ot = w >> 1;
    const int C0 = blockIdx.x * 64;
    const int by = blockIdx.y;                // 8 conv rows, 2 pooled rows
    const int R0 = by * 8;
    const int b = blockIdx.z;

    // ---- stage x rows R0..R0+9: transpose [ic][h][w] -> [row][px][8ic], hi/lo split ----
    const float* xb = x + (size_t)b * 524288;
    for (int i = tid; i < 660; i += 256) {
        int row = i / 66, px = i - row * 66;
        int gr = R0 + row, gc = C0 + px;
        bool ok = (gr < 256) && (gc < 256);
        const float* p = xb + gr * 256 + gc;
        unsigned hi[4], lo[4];
        #pragma unroll
        for (int jj = 0; jj < 4; ++jj) {
            float v0 = ok ? p[(2 * jj) * 65536] : 0.0f;
            float v1 = ok ? p[(2 * jj + 1) * 65536] : 0.0f;
            unsigned short h0 = (unsigned short)(__float_as_uint(v0) >> 16);  // trunc hi
            unsigned short h1 = (unsigned short)(__float_as_uint(v1) >> 16);
            unsigned short l0 = f2bf_rne(v0 - bf2f(h0));
            unsigned short l1 = f2bf_rne(v1 - bf2f(h1));
            hi[jj] = (unsigned)h0 | ((unsigned)h1 << 16);
            lo[jj] = (unsigned)l0 | ((unsigned)l1 << 16);
        }
        uint4* dst = (uint4*)(xs + i * 48);
        dst[0] = make_uint4(hi[0], hi[1], hi[2], hi[3]);
        dst[1] = make_uint4(lo[0], lo[1], lo[2], lo[3]);
    }
    if (tid == 0) {   // B=1.0 slot for the bias K-step (hh5=1, s=4, j=0 -> k=72)
        *(uint4*)(xs + ONES_OFF)      = make_uint4(0x3F80u, 0u, 0u, 0u);
        *(uint4*)(xs + ONES_OFF + 16) = make_uint4(0u, 0u, 0u, 0u);
    }
    __syncthreads();

    // ---- A fragments from prepped global (coalesced 1KB per load, L2-hot) ----
    bf16x8 af[5][2];
    #pragma unroll
    for (int s = 0; s < 5; ++s)
        #pragma unroll
        for (int hf = 0; hf < 2; ++hf)
            af[s][hf] = *(const bf16x8*)(wg + (s * 2 + hf) * 1024 + ot * 512 + l * 8);

    // per-Kstep tap: hh5=0 -> taps 0,2,4,6,8 ; hh5=1 -> 1,3,5,7,bias
    const int KHe[5] = {0, 0, 1, 2, 2}, KWe[5] = {0, 2, 1, 0, 2};
    const int KHo[5] = {0, 1, 1, 2, 0}, KWo[5] = {1, 0, 2, 1, 0};
    int baseOff[5];
    #pragma unroll
    for (int s = 0; s < 5; ++s) {
        int kh = hh5 ? KHo[s] : KHe[s];
        int kw = hh5 ? KWo[s] : KWe[s];
        baseOff[s] = kh * 3168 + (po * 32 + ll + kw) * 48;
    }

    const bool pxV = (C0 + po * 32 + ll) < 254;
    const int pcol = blockIdx.x * 16 + po * 8 + (ll >> 2);
    float pm[16];
    float sacc[4] = {0.f, 0.f, 0.f, 0.f}, qacc[4] = {0.f, 0.f, 0.f, 0.f};
    #pragma unroll
    for (int j = 0; j < 16; ++j) pm[j] = -3.4e38f;

    #pragma unroll 1
    for (int r = 0; r < 8; ++r) {
        f32x16 acc;
        #pragma unroll
        for (int j = 0; j < 16; ++j) acc[j] = 0.0f;
        const unsigned char* xr = xs + r * 3168;
        #pragma unroll
        for (int s = 0; s < 5; ++s) {
            const unsigned char* bp = (s == 4 && hh5) ? (xs + ONES_OFF)
                                                      : (xr + baseOff[s]);
            bf16x8 Bh = *(const bf16x8*)bp;
            bf16x8 Bl = *(const bf16x8*)(bp + 16);
            acc = __builtin_amdgcn_mfma_f32_32x32x16_bf16(af[s][0], Bh, acc, 0, 0, 0);
            acc = __builtin_amdgcn_mfma_f32_32x32x16_bf16(af[s][1], Bh, acc, 0, 0, 0);
            acc = __builtin_amdgcn_mfma_f32_32x32x16_bf16(af[s][0], Bl, acc, 0, 0, 0);
        }
        const bool sv = ((R0 + r) < 254) && pxV;
        #pragma unroll
        for (int reg = 0; reg < 16; ++reg) {
            const float v = acc[reg];
            pm[reg] = fmaxf(pm[reg], v);
            const float vm = sv ? v : 0.0f;
            sacc[reg >> 2] += vm;
            qacc[reg >> 2] = fmaf(vm, vm, qacc[reg >> 2]);
        }
        if ((r & 3) == 3) {                      // finish pooled row tY
            const int tY = 2 * by + (r >> 2);
            #pragma unroll
            for (int reg = 0; reg < 16; ++reg) {
                float m = dppmax(pm[reg], 0xB1);  // xor 1 in px quad
                pm[reg] = dppmax(m, 0x4E);        // xor 2
            }
            if (tY < 63 && (ll & 3) == 0 && pcol < 63) {
                #pragma unroll
                for (int reg = 0; reg < 16; ++reg) {
                    int oc = ot * 32 + (reg & 3) + 8 * (reg >> 2) + 4 * hh5;
                    pooled[((b * 64 + oc) * 63 + tY) * 63 + pcol] = pm[reg];
                }
            }
            #pragma unroll
            for (int reg = 0; reg < 16; ++reg) pm[reg] = -3.4e38f;
        }
    }

    // ---- stats reduce within 32-lane halves (halves hold even/odd groups) ----
    #pragma unroll
    for (int m = 1; m <= 16; m <<= 1) {
        #pragma unroll
        for (int j = 0; j < 4; ++j) {
            sacc[j] += __shfl_xor(sacc[j], m, 64);
            qacc[j] += __shfl_xor(qacc[j], m, 64);
        }
    }
    if (ll == 0) {
        #pragma unroll
        for (int j = 0; j < 4; ++j) {
            int g = ot * 8 + 2 * j + hh5;
            atomicAdd(&stats[b * 16 + g], sacc[j]);
            atomicAdd(&stats[512 + b * 16 + g], qacc[j]);
        }
    }
}

__global__ __launch_bounds__(256) void finalize_affine_clamp(
    float* __restrict__ out, const float* __restrict__ stats,
    const float* __restrict__ gnw, const float* __restrict__ gnb,
    const float* __restrict__ scale)
{
    const int bc = blockIdx.y;                 // 0..2047
    const int b = bc >> 6, c = bc & 63, g = c >> 2;
    const float sum = stats[b * 16 + g];
    const float ssq = stats[512 + b * 16 + g];
    const float invN = 1.0f / NPIX;
    const float mean = sum * invN;
    const float var  = ssq * invN - mean * mean;
    const float rs   = rsqrtf(var + 1e-5f);
    const float A  = rs * gnw[c] * scale[c];
    const float Bv = (gnb[c] - mean * rs * gnw[c]) * scale[c];
    const int base = bc * 3969;
    #pragma unroll
    for (int k = 0; k < 4; ++k) {
        int e = blockIdx.x * 1024 + k * 256 + threadIdx.x;
        if (e < 3969) {
            float v = fmaf(A, out[base + e], Bv);
            out[base + e] = fminf(fmaxf(v, 0.0f), 1.0f);
        }
    }
}

extern "C" void kernel_launch(void* const* d_in, const int* in_sizes, int n_in,
                              void* d_out, int out_size, void* d_ws, size_t ws_size,
                              hipStream_t stream) {
    const float* x     = (const float*)d_in[0];
    const float* cw    = (const float*)d_in[1];
    const float* cb    = (const float*)d_in[2];
    const float* gnw   = (const float*)d_in[3];
    const float* gnb   = (const float*)d_in[4];
    const float* scale = (const float*)d_in[5];
    float* out   = (float*)d_out;
    float* stats = (float*)d_ws;                                  // 1024 f32
    unsigned short* wg = (unsigned short*)((float*)d_ws + 1024);  // 10240 bf16

    hipMemsetAsync(d_ws, 0, 1024 * sizeof(float), stream);

    prep_weights<<<40, 256, 0, stream>>>(cw, cb, wg);

    dim3 grid1(4, 32, 32);
    conv_mfma<<<grid1, 256, 0, stream>>>(x, wg, out, stats);

    dim3 grid2(4, 2048, 1);
    finalize_affine_clamp<<<grid2, 256, 0, stream>>>(out, stats, gnw, gnb, scale);
}

// Round 8
// 256.822 us; speedup vs baseline: 3.4968x; 1.0282x over previous
//
#include <hip/hip_runtime.h>

// Conv2d(8->64,3x3,VALID)+bias -> GroupNorm(16) -> scale[c] -> MaxPool4x4 -> clip[0,1]
// x: [32,8,256,256] f32 -> out: [32,64,63,63] f32.
//
// R8: = R6/R7 structure + ILP-2 MFMA chains.
//  - R7 diagnosis: MfmaUtil 16% == issued work / duration; serial 15-MFMA acc chain
//    (latency ~300cy vs 120cy issue) + 4 blocks/CU -> latency-bound.
//  - Fix: 2 rows per iteration, two independent accumulators, interleaved issue.
//  - prep_weights also zeroes stats (drops the memset dispatch).
//  - A-fragments loaded before staging (latency hidden under stage phase).

typedef __attribute__((ext_vector_type(8))) short bf16x8;
typedef __attribute__((ext_vector_type(16))) float f32x16;

#define NPIX 258064.0f   // 4 * 254 * 254 per (b, group)
#define ONES_OFF 31680   // byte offset of the B=1.0 slot in xs

__device__ __forceinline__ unsigned short f2bf_rne(float f) {
    unsigned u = __float_as_uint(f);
    u += 0x7FFFu + ((u >> 16) & 1u);
    return (unsigned short)(u >> 16);
}
__device__ __forceinline__ float bf2f(unsigned short h) {
    return __uint_as_float(((unsigned)h) << 16);
}
__device__ __forceinline__ float dppmax(float v, const int ctrl) {
    int o;
    if (ctrl == 0xB1) o = __builtin_amdgcn_mov_dpp(__float_as_int(v), 0xB1, 0xF, 0xF, true);
    else              o = __builtin_amdgcn_mov_dpp(__float_as_int(v), 0x4E, 0xF, 0xF, true);
    return fmaxf(v, __int_as_float(o));
}

// ---- one-time weight prep + stats zero ----
// wg[(s*2+half)*1024 + ot*512 + lane*8 + j]
__global__ __launch_bounds__(256) void prep_weights(
    const float* __restrict__ cw, const float* __restrict__ cb,
    unsigned short* __restrict__ wg, float* __restrict__ stats)
{
    const int e = blockIdx.x * 256 + threadIdx.x;
    if (e < 1024) stats[e] = 0.0f;
    if (e >= 10240) return;
    const int j = e & 7, lane = (e >> 3) & 63, ot = (e >> 9) & 1;
    const int half = (e >> 10) & 1, s = e >> 11;
    const int oc = ot * 32 + (lane & 31), hh5 = lane >> 5;
    const int k = s * 16 + hh5 * 8 + j;
    float wv = 0.0f;
    if (k < 72)       wv = cw[oc * 72 + (k & 7) * 9 + (k >> 3)];
    else if (k == 72) wv = cb[oc];          // bias rides the pad K-slot
    const unsigned short hi = f2bf_rne(wv);
    const unsigned short lo = f2bf_rne(wv - bf2f(hi));
    wg[e] = half ? lo : hi;
}

__global__ __launch_bounds__(256, 4) void conv_mfma(
    const float* __restrict__ x, const unsigned short* __restrict__ wg,
    float* __restrict__ pooled, float* __restrict__ stats)
{
    __shared__ __align__(16) unsigned char xs[10 * 66 * 48 + 32];  // 31712 B

    const int tid = threadIdx.x;
    const int l = tid & 63, w = tid >> 6;
    const int ll = l & 31, hh5 = l >> 5;
    const int po = w & 1, ot = w >> 1;
    const int C0 = blockIdx.x * 64;
    const int by = blockIdx.y;                // 8 conv rows = 2 pooled rows
    const int R0 = by * 8;
    const int b = blockIdx.z;

    // ---- A fragments: issue global loads FIRST (latency hides under staging) ----
    bf16x8 af[5][2];
    #pragma unroll
    for (int s = 0; s < 5; ++s)
        #pragma unroll
        for (int hf = 0; hf < 2; ++hf)
            af[s][hf] = *(const bf16x8*)(wg + (s * 2 + hf) * 1024 + ot * 512 + l * 8);

    // ---- stage x rows R0..R0+9: transpose [ic][h][w] -> [row][px][8ic], hi/lo split ----
    const float* xb = x + (size_t)b * 524288;
    for (int i = tid; i < 660; i += 256) {
        int row = i / 66, px = i - row * 66;
        int gr = R0 + row, gc = C0 + px;
        bool ok = (gr < 256) && (gc < 256);
        const float* p = xb + gr * 256 + gc;
        unsigned hi[4], lo[4];
        #pragma unroll
        for (int jj = 0; jj < 4; ++jj) {
            float v0 = ok ? p[(2 * jj) * 65536] : 0.0f;
            float v1 = ok ? p[(2 * jj + 1) * 65536] : 0.0f;
            unsigned short h0 = (unsigned short)(__float_as_uint(v0) >> 16);  // trunc hi
            unsigned short h1 = (unsigned short)(__float_as_uint(v1) >> 16);
            unsigned short l0 = f2bf_rne(v0 - bf2f(h0));
            unsigned short l1 = f2bf_rne(v1 - bf2f(h1));
            hi[jj] = (unsigned)h0 | ((unsigned)h1 << 16);
            lo[jj] = (unsigned)l0 | ((unsigned)l1 << 16);
        }
        uint4* dst = (uint4*)(xs + i * 48);
        dst[0] = make_uint4(hi[0], hi[1], hi[2], hi[3]);
        dst[1] = make_uint4(lo[0], lo[1], lo[2], lo[3]);
    }
    if (tid == 0) {   // B=1.0 slot for the bias K-step (hh5=1, s=4 -> k=72)
        *(uint4*)(xs + ONES_OFF)      = make_uint4(0x3F80u, 0u, 0u, 0u);
        *(uint4*)(xs + ONES_OFF + 16) = make_uint4(0u, 0u, 0u, 0u);
    }
    __syncthreads();

    // per-Kstep tap: hh5=0 -> taps 0,2,4,6,8 ; hh5=1 -> 1,3,5,7,bias
    const int KHe[5] = {0, 0, 1, 2, 2}, KWe[5] = {0, 2, 1, 0, 2};
    const int KHo[5] = {0, 1, 1, 2, 0}, KWo[5] = {1, 0, 2, 1, 0};
    int baseOff[5];
    #pragma unroll
    for (int s = 0; s < 5; ++s) {
        int kh = hh5 ? KHo[s] : KHe[s];
        int kw = hh5 ? KWo[s] : KWe[s];
        baseOff[s] = kh * 3168 + (po * 32 + ll + kw) * 48;
    }

    const bool pxV = (C0 + po * 32 + ll) < 254;
    const int pcol = blockIdx.x * 16 + po * 8 + (ll >> 2);
    float pm[16];
    float sacc[4] = {0.f, 0.f, 0.f, 0.f}, qacc[4] = {0.f, 0.f, 0.f, 0.f};
    #pragma unroll
    for (int j = 0; j < 16; ++j) pm[j] = -3.4e38f;

    #pragma unroll 1
    for (int rp = 0; rp < 4; ++rp) {              // rows 2rp, 2rp+1: two indep chains
        f32x16 accP, accQ;
        #pragma unroll
        for (int j = 0; j < 16; ++j) { accP[j] = 0.0f; accQ[j] = 0.0f; }
        const unsigned char* xrP = xs + (2 * rp) * 3168;
        #pragma unroll
        for (int s = 0; s < 5; ++s) {
            const bool ones = (s == 4) && hh5;
            const unsigned char* bpP = ones ? (xs + ONES_OFF) : (xrP + baseOff[s]);
            const unsigned char* bpQ = ones ? (xs + ONES_OFF) : (xrP + 3168 + baseOff[s]);
            bf16x8 BhP = *(const bf16x8*)bpP;
            bf16x8 BlP = *(const bf16x8*)(bpP + 16);
            bf16x8 BhQ = *(const bf16x8*)bpQ;
            bf16x8 BlQ = *(const bf16x8*)(bpQ + 16);
            accP = __builtin_amdgcn_mfma_f32_32x32x16_bf16(af[s][0], BhP, accP, 0, 0, 0);
            accQ = __builtin_amdgcn_mfma_f32_32x32x16_bf16(af[s][0], BhQ, accQ, 0, 0, 0);
            accP = __builtin_amdgcn_mfma_f32_32x32x16_bf16(af[s][1], BhP, accP, 0, 0, 0);
            accQ = __builtin_amdgcn_mfma_f32_32x32x16_bf16(af[s][1], BhQ, accQ, 0, 0, 0);
            accP = __builtin_amdgcn_mfma_f32_32x32x16_bf16(af[s][0], BlP, accP, 0, 0, 0);
            accQ = __builtin_amdgcn_mfma_f32_32x32x16_bf16(af[s][0], BlQ, accQ, 0, 0, 0);
        }
        const bool svP = ((R0 + 2 * rp) < 254) && pxV;
        const bool svQ = ((R0 + 2 * rp + 1) < 254) && pxV;
        #pragma unroll
        for (int reg = 0; reg < 16; ++reg) {
            const float vP = accP[reg], vQ = accQ[reg];
            pm[reg] = fmaxf(pm[reg], fmaxf(vP, vQ));
            const float mP = svP ? vP : 0.0f;
            const float mQ = svQ ? vQ : 0.0f;
            sacc[reg >> 2] += mP + mQ;
            qacc[reg >> 2] = fmaf(mP, mP, fmaf(mQ, mQ, qacc[reg >> 2]));
        }
        if (rp & 1) {                              // finished pooled row tY
            const int tY = 2 * by + (rp >> 1);
            #pragma unroll
            for (int reg = 0; reg < 16; ++reg) {
                float m = dppmax(pm[reg], 0xB1);   // xor 1 in px quad
                pm[reg] = dppmax(m, 0x4E);         // xor 2
            }
            if (tY < 63 && (ll & 3) == 0 && pcol < 63) {
                #pragma unroll
                for (int reg = 0; reg < 16; ++reg) {
                    int oc = ot * 32 + (reg & 3) + 8 * (reg >> 2) + 4 * hh5;
                    pooled[((b * 64 + oc) * 63 + tY) * 63 + pcol] = pm[reg];
                }
            }
            #pragma unroll
            for (int reg = 0; reg < 16; ++reg) pm[reg] = -3.4e38f;
        }
    }

    // ---- stats reduce within 32-lane halves (halves hold even/odd groups) ----
    #pragma unroll
    for (int m = 1; m <= 16; m <<= 1) {
        #pragma unroll
        for (int j = 0; j < 4; ++j) {
            sacc[j] += __shfl_xor(sacc[j], m, 64);
            qacc[j] += __shfl_xor(qacc[j], m, 64);
        }
    }
    if (ll == 0) {
        #pragma unroll
        for (int j = 0; j < 4; ++j) {
            int g = ot * 8 + 2 * j + hh5;
            atomicAdd(&stats[b * 16 + g], sacc[j]);
            atomicAdd(&stats[512 + b * 16 + g], qacc[j]);
        }
    }
}

__global__ __launch_bounds__(256) void finalize_affine_clamp(
    float* __restrict__ out, const float* __restrict__ stats,
    const float* __restrict__ gnw, const float* __restrict__ gnb,
    const float* __restrict__ scale)
{
    const int t = blockIdx.x * 256 + threadIdx.x;    // float4 index
    if (t >= 2032128) return;                        // 32*64*3969/4
    float4 v = reinterpret_cast<float4*>(out)[t];
    float r[4] = {v.x, v.y, v.z, v.w};
    const int I0 = t * 4;
    const int bc0 = I0 / 3969;
    const int bc3 = (I0 + 3) / 3969;
    const float invN = 1.0f / NPIX;
    if (bc0 == bc3) {
        const int b = bc0 >> 6, c = bc0 & 63, g = c >> 2;
        const float mean = stats[b * 16 + g] * invN;
        const float var  = stats[512 + b * 16 + g] * invN - mean * mean;
        const float rs   = rsqrtf(var + 1e-5f);
        const float A  = rs * gnw[c] * scale[c];
        const float Bv = (gnb[c] - mean * rs * gnw[c]) * scale[c];
        #pragma unroll
        for (int j = 0; j < 4; ++j)
            r[j] = fminf(fmaxf(fmaf(A, r[j], Bv), 0.0f), 1.0f);
    } else {
        #pragma unroll
        for (int j = 0; j < 4; ++j) {
            const int bc = (I0 + j) / 3969;
            const int b = bc >> 6, c = bc & 63, g = c >> 2;
            const float mean = stats[b * 16 + g] * invN;
            const float var  = stats[512 + b * 16 + g] * invN - mean * mean;
            const float rs   = rsqrtf(var + 1e-5f);
            const float A  = rs * gnw[c] * scale[c];
            const float Bv = (gnb[c] - mean * rs * gnw[c]) * scale[c];
            r[j] = fminf(fmaxf(fmaf(A, r[j], Bv), 0.0f), 1.0f);
        }
    }
    reinterpret_cast<float4*>(out)[t] = make_float4(r[0], r[1], r[2], r[3]);
}

extern "C" void kernel_launch(void* const* d_in, const int* in_sizes, int n_in,
                              void* d_out, int out_size, void* d_ws, size_t ws_size,
                              hipStream_t stream) {
    const float* x     = (const float*)d_in[0];
    const float* cw    = (const float*)d_in[1];
    const float* cb    = (const float*)d_in[2];
    const float* gnw   = (const float*)d_in[3];
    const float* gnb   = (const float*)d_in[4];
    const float* scale = (const float*)d_in[5];
    float* out   = (float*)d_out;
    float* stats = (float*)d_ws;                                  // 1024 f32
    unsigned short* wg = (unsigned short*)((float*)d_ws + 1024);  // 10240 bf16

    prep_weights<<<40, 256, 0, stream>>>(cw, cb, wg, stats);

    dim3 grid1(4, 32, 32);
    conv_mfma<<<grid1, 256, 0, stream>>>(x, wg, out, stats);

    finalize_affine_clamp<<<(2032128 + 255) / 256, 256, 0, stream>>>(out, stats, gnw, gnb, scale);
}